// Round 7
// baseline (275.806 us; speedup 1.0000x reference)
//
#include <hip/hip_runtime.h>
#include <stdint.h>

#define DMODEL 768
#define DFC    3072
#define NHEAD  12
#define DHEAD  64
#define BSZ    4
#define SEQ    1024
#define NTOK   (BSZ*SEQ)
#define QKVN   (3*DMODEL)   // 2304

typedef unsigned short u16;
typedef unsigned int   u32;
typedef unsigned long long u64;
typedef __bf16 bf16_t;
typedef bf16_t bf16x8 __attribute__((ext_vector_type(8)));
typedef bf16_t bf16x2 __attribute__((ext_vector_type(2)));
typedef float  f32x4  __attribute__((ext_vector_type(4)));
typedef float  f32x16 __attribute__((ext_vector_type(16)));
typedef u32    u32x2  __attribute__((ext_vector_type(2)));

__device__ __forceinline__ u16 f2b(float f) {  // native RNE cast
  __bf16 h = (__bf16)f;
  return __builtin_bit_cast(u16, h);
}
__device__ __forceinline__ float b2f(u16 u) {
  return __builtin_bit_cast(float, (u32)u << 16);
}
__device__ __forceinline__ u32 pk2(float a, float b) {  // -> v_cvt_pk_bf16_f32
  bf16x2 t = {(__bf16)a, (__bf16)b};
  return __builtin_bit_cast(u32, t);
}

__device__ __forceinline__ void gload_lds16(const void* g, void* l) {
  __builtin_amdgcn_global_load_lds(
      (const __attribute__((address_space(1))) void*)g,
      (__attribute__((address_space(3))) void*)l, 16, 0, 0);
}

// ---------------- fused prep: cast + 6 weight transposes + mask pack ----------------
__global__ __launch_bounds__(256) void mega_prep(
    const float* __restrict__ x, u16* __restrict__ XB,
    const float* __restrict__ WQ, const float* __restrict__ WK,
    const float* __restrict__ WV, const float* __restrict__ Wfc,
    const float* __restrict__ W1, const float* __restrict__ W2,
    u16* __restrict__ WQKVT, u16* __restrict__ WFCT,
    u16* __restrict__ W1T, u16* __restrict__ W2T,
    const int* __restrict__ mask, u64* __restrict__ MP) {
  __shared__ float tile[32][33];
  int bid = blockIdx.x, tid = threadIdx.x;

  if (bid < 3072) {  // cast x -> bf16
    int i = bid * 256 + tid;
    float4 v = ((const float4*)x)[i];
    ushort4 o;
    o.x = f2b(v.x); o.y = f2b(v.y); o.z = f2b(v.z); o.w = f2b(v.w);
    ((ushort4*)XB)[i] = o;
    return;
  }
  if (bid >= 9984) {  // pack mask
    int t = bid - 9984;
    int w = tid >> 6, lane = tid & 63;
    int idx = t * 4 + w;
    u64 bal = __ballot(mask[(size_t)idx * 64 + lane] != 0);
    if (lane == 0) MP[idx] = bal;
    return;
  }
  const float* in; u16* outp; int K, N, bx, by;
  if (bid < 5376) {
    int r = bid - 3072, which = r / 576, t = r % 576;
    in = which == 0 ? WQ : which == 1 ? WK : which == 2 ? WV : Wfc;
    outp = which < 3 ? WQKVT + (size_t)which * DMODEL * DMODEL : WFCT;
    K = DMODEL; N = DMODEL; bx = (t % 24) * 32; by = (t / 24) * 32;
  } else if (bid < 7680) {
    int t = bid - 5376;
    in = W1; outp = W1T; K = DMODEL; N = DFC;
    bx = (t % 96) * 32; by = (t / 96) * 32;
  } else {
    int t = bid - 7680;
    in = W2; outp = W2T; K = DFC; N = DMODEL;
    bx = (t % 24) * 32; by = (t / 24) * 32;
  }
  int tx = tid & 31, ty = tid >> 5;
#pragma unroll
  for (int i = 0; i < 4; ++i)
    tile[ty + i * 8][tx] = in[(size_t)(by + ty + i * 8) * N + bx + tx];
  __syncthreads();
#pragma unroll
  for (int i = 0; i < 4; ++i)
    outp[(size_t)(bx + ty + i * 8) * K + by + tx] = f2b(tile[tx][ty + i * 8]);
}

// V columns of QKVM -> VT[b*H+h][d][s]
__global__ __launch_bounds__(256) void build_vt(const u16* __restrict__ QKVM,
                                                u16* __restrict__ VT) {
  __shared__ u16 t[64][72];
  int st = blockIdx.x, h = blockIdx.y, b = blockIdx.z;
  int tid = threadIdx.x;
  const u16* src = QKVM + ((size_t)(b * SEQ + st * 64)) * QKVN + 2 * DMODEL + h * DHEAD;
#pragma unroll
  for (int p = 0; p < 2; ++p) {
    int s = (p * 256 + tid) >> 3, c8 = tid & 7;
    *(uint4*)&t[s][c8 * 8] = *(const uint4*)&src[(size_t)s * QKVN + c8 * 8];
  }
  __syncthreads();
  u16* dst = VT + ((size_t)(b * NHEAD + h) * 64) * SEQ + st * 64;
#pragma unroll
  for (int p = 0; p < 2; ++p) {
    int d = (p * 256 + tid) >> 3, s8 = tid & 7;
    union { uint4 v; u16 s[8]; } o;
#pragma unroll
    for (int j = 0; j < 8; ++j) o.s[j] = t[s8 * 8 + j][d];
    *(uint4*)&dst[(size_t)d * SEQ + s8 * 8] = o.v;
  }
}

// ---------------- GEMM: C[M][N] = A[M][K] (bf16) @ Bt[N][K]^T (bf16) ----------------
// MODE 0: bf16 | 2: +bias+relu bf16 | 4: f32 partial (z-strided) | 5: bf16 partial (pA/pB)
template <int MODE, int SPLIT>
__global__ __launch_bounds__(256) void gemm_bt(const u16* __restrict__ A,
                                               const u16* __restrict__ Bt,
                                               void* __restrict__ Cout,
                                               const float* __restrict__ bias,
                                               u16* __restrict__ pA, u16* __restrict__ pB,
                                               int M, int N, int K) {
  __shared__ __align__(16) u16 ldsA[2][128 * 32];
  __shared__ __align__(16) u16 ldsB[2][128 * 32];
  int tid = threadIdx.x;
  int lane = tid & 63, l15 = lane & 15, g = lane >> 4;
  int w = tid >> 6, wm = w >> 1, wn = w & 1;

  // XCD-bijective block swizzle (all grids here have nwg % 8 == 0)
  int gx = gridDim.x;
  int bid = blockIdx.y * gx + blockIdx.x;
  int nwg = gx * gridDim.y;
  int wgid = ((nwg & 7) == 0) ? ((bid & 7) * (nwg >> 3) + (bid >> 3)) : bid;
  int m0 = (wgid / gx) * 128, n0 = (wgid % gx) * 128;

  int KS = K / SPLIT;
  int k0 = blockIdx.z * KS;
  int NT = KS >> 5;

  f32x4 acc[4][4];
#pragma unroll
  for (int i = 0; i < 4; ++i)
#pragma unroll
    for (int j = 0; j < 4; ++j) acc[i][j] = (f32x4){0.f, 0.f, 0.f, 0.f};

  const u16* gabase = A + (size_t)m0 * K + k0;
  const u16* gbbase = Bt + (size_t)n0 * K + k0;
  int wbase = tid & ~63;
  int lswz = (lane & 3) ^ ((lane >> 3) & 3);  // source-side 16B slot swizzle

  auto stage = [&](int kt, int buf) {
#pragma unroll
    for (int p = 0; p < 2; ++p) {
      int c = p * 256 + tid;
      int row = c >> 2;
      size_t goff = (size_t)row * K + kt * 32 + lswz * 8;
      gload_lds16(gabase + goff, &ldsA[buf][(p * 256 + wbase) * 8]);
      gload_lds16(gbbase + goff, &ldsB[buf][(p * 256 + wbase) * 8]);
    }
  };

  int rswz = (l15 >> 1) & 3;  // read-side swizzle

  stage(0, 0);
  __syncthreads();
  for (int kt = 0; kt < NT; ++kt) {
    int cur = kt & 1;
    if (kt + 1 < NT) stage(kt + 1, cur ^ 1);
    bf16x8 af[4], bfr[4];
#pragma unroll
    for (int i = 0; i < 4; ++i) {
      af[i]  = *(const bf16x8*)&ldsA[cur][(wm * 64 + i * 16 + l15) * 32 + (g ^ rswz) * 8];
      bfr[i] = *(const bf16x8*)&ldsB[cur][(wn * 64 + i * 16 + l15) * 32 + (g ^ rswz) * 8];
    }
#pragma unroll
    for (int i = 0; i < 4; ++i)
#pragma unroll
      for (int j = 0; j < 4; ++j)
        acc[i][j] = __builtin_amdgcn_mfma_f32_16x16x32_bf16(af[i], bfr[j], acc[i][j], 0, 0, 0);
    __syncthreads();
  }

  u16* pdst = nullptr;
  if (MODE == 5)
    pdst = ((blockIdx.z & 2) ? pB : pA) + (size_t)(blockIdx.z & 1) * M * N;
#pragma unroll
  for (int i = 0; i < 4; ++i) {
#pragma unroll
    for (int j = 0; j < 4; ++j) {
#pragma unroll
      for (int r = 0; r < 4; ++r) {
        int row = m0 + wm * 64 + i * 16 + g * 4 + r;
        int col = n0 + wn * 64 + j * 16 + l15;
        float v = acc[i][j][r];
        if (MODE == 2) {
          v += bias[col];
          v = v > 0.f ? v : 0.f;
        }
        if (MODE == 0 || MODE == 2)
          ((u16*)Cout)[(size_t)row * N + col] = f2b(v);
        else if (MODE == 4)
          ((float*)Cout)[(size_t)blockIdx.z * M * N + (size_t)row * N + col] = v;
        else
          pdst[(size_t)row * N + col] = f2b(v);
      }
    }
  }
}

// ---------------- attention (32x32 MFMA, swapped QK^T, in-register P) ----------------
// 2 waves x 32 q each; grid 768 XCD-bijective. S^T = mfma32(K,Q): lane(l31,hi) holds
// S[key=(r&3)+8*(r>>2)+4hi][q=l31]. P -> PV A-frag via cvt_pk + permlane32_swap builtin
// (T12 recipe: r = swap(w_early, w_late); r[0]=j{0,1} word, r[1]=j{4,5} word).
__global__ __launch_bounds__(128) void attn_kernel(const u16* __restrict__ QKVM,
                                                   const u16* __restrict__ VT,
                                                   const u64* __restrict__ MP,
                                                   u16* __restrict__ Om) {
  __shared__ __align__(16) u16 ldsK[2][64 * 64];
  __shared__ __align__(16) u16 ldsV[2][64 * 64];

  int bid = blockIdx.x;
  int logical = (bid & 7) * 96 + (bid >> 3);
  int qt = logical & 15, hb = logical >> 4;
  int h = hb % NHEAD, b = hb / NHEAD;

  int tid = threadIdx.x, w = tid >> 6, lane = tid & 63;
  int l31 = lane & 31, hi = lane >> 5, l7 = l31 & 7;
  int q0w = qt * 64 + w * 32;

  const u16* Qb = QKVM + (size_t)(b * SEQ) * QKVN + h * DHEAD;
  const u16* Kb = QKVM + (size_t)(b * SEQ) * QKVN + DMODEL + h * DHEAD;
  const u16* Vb = VT + (size_t)(b * NHEAD + h) * 64 * SEQ;

  // Q frags (B operand): col=q=l31, slot j -> d = dt*16 + hi*8 + j
  bf16x8 qf[4];
#pragma unroll
  for (int dt = 0; dt < 4; ++dt)
    qf[dt] = *(const bf16x8*)&Qb[(size_t)(q0w + l31) * QKVN + dt * 16 + hi * 8];

  // staging: wave w round p covers rows [p*16+w*8, +8); lane dest linear, src swizzled
  int r8 = lane >> 3, sl = lane & 7, slg = sl ^ r8;
  auto stage = [&](int kt, int buf) {
#pragma unroll
    for (int p = 0; p < 4; ++p) {
      int row = p * 16 + w * 8 + r8;
      gload_lds16(Kb + (size_t)(kt * 64 + row) * QKVN + slg * 8, &ldsK[buf][(p * 16 + w * 8) * 64]);
      gload_lds16(Vb + (size_t)row * SEQ + kt * 64 + slg * 8, &ldsV[buf][(p * 16 + w * 8) * 64]);
    }
  };

  f32x16 acc[2];
#pragma unroll
  for (int d2 = 0; d2 < 2; ++d2)
#pragma unroll
    for (int r = 0; r < 16; ++r) acc[d2][r] = 0.f;
  float ps = 0.f;

  const float SC2 = 0.41650835f;  // (1/sqrt(12)) * log2(e)

  stage(0, 0);
  __syncthreads();

  for (int kt = 0; kt < SEQ / 64; ++kt) {
    int cur = kt & 1;
    if (kt + 1 < SEQ / 64) stage(kt + 1, cur ^ 1);

    u64 mw = MP[((size_t)(b * SEQ + q0w + l31) << 4) | kt];

#pragma unroll
    for (int kk = 0; kk < 2; ++kk) {
      // S^T: A = K (row=key32=l31), B = Q (col=q=l31)
      f32x16 sacc;
#pragma unroll
      for (int r = 0; r < 16; ++r) sacc[r] = 0.f;
#pragma unroll
      for (int dt = 0; dt < 4; ++dt) {
        bf16x8 kf = *(const bf16x8*)((const char*)&ldsK[cur][0] +
                      (kk * 32 + l31) * 128 + (((dt * 2 + hi) ^ l7) << 4));
        sacc = __builtin_amdgcn_mfma_f32_32x32x16_bf16(kf, qf[dt], sacc, 0, 0, 0);
      }

      // mask + exp (keys this lane holds: (r&3)+8*(r>>2)+4hi within kk*32 block)
      u32 mh = (u32)(mw >> (kk * 32 + 4 * hi));
      float p[16];
#pragma unroll
      for (int r = 0; r < 16; ++r) {
        float pe = __builtin_amdgcn_exp2f(sacc[r] * SC2);
        p[r] = ((mh >> ((r & 3) + 8 * (r >> 2))) & 1u) ? pe : 0.f;
        ps += p[r];
      }

      // pack + permlane32_swap -> A-frag slot (hi,j) holds key hi*8+j of the 16-block
#pragma unroll
      for (int kt2 = 0; kt2 < 2; ++kt2) {
        u32 w0 = pk2(p[kt2 * 8 + 0], p[kt2 * 8 + 1]);  // keys {0,1}+4hi
        u32 w1 = pk2(p[kt2 * 8 + 2], p[kt2 * 8 + 3]);  // keys {2,3}+4hi
        u32 w2 = pk2(p[kt2 * 8 + 4], p[kt2 * 8 + 5]);  // keys {8,9}+4hi
        u32 w3 = pk2(p[kt2 * 8 + 6], p[kt2 * 8 + 7]);  // keys {10,11}+4hi
        u32x2 rA = __builtin_amdgcn_permlane32_swap(w0, w2, false, false);
        u32x2 rB = __builtin_amdgcn_permlane32_swap(w1, w3, false, false);
        union { u32 u[4]; bf16x8 v; } pa;
        pa.u[0] = rA[0];  // j={0,1}
        pa.u[1] = rB[0];  // j={2,3}
        pa.u[2] = rA[1];  // j={4,5}
        pa.u[3] = rB[1];  // j={6,7}
#pragma unroll
        for (int d2 = 0; d2 < 2; ++d2) {
          bf16x8 vf = *(const bf16x8*)((const char*)&ldsV[cur][0] +
                        (d2 * 32 + l31) * 128 + (((kk * 4 + kt2 * 2 + hi) ^ l7) << 4));
          acc[d2] = __builtin_amdgcn_mfma_f32_32x32x16_bf16(pa.v, vf, acc[d2], 0, 0, 0);
        }
      }
    }
    __syncthreads();  // drains prefetch vmcnt; protects K/V dbuf
  }

  // softmax denominator: q = l31 is lane-local; total = hi=0 + hi=1 halves
  float pst = ps + __shfl_xor(ps, 32);
  float invp = 1.f / pst;
  float sc[16];
#pragma unroll
  for (int r = 0; r < 16; ++r)
    sc[r] = __shfl(invp, (r & 3) + 8 * (r >> 2) + 4 * hi);

#pragma unroll
  for (int d2 = 0; d2 < 2; ++d2)
#pragma unroll
    for (int r = 0; r < 16; ++r) {
      int ql = (r & 3) + 8 * (r >> 2) + 4 * hi;
      Om[(size_t)(b * SEQ + q0w + ql) * DMODEL + h * DHEAD + d2 * 32 + l31] =
          f2b(acc[d2][r] * sc[r]);
    }
}

// ---------------- LN1: layernorm(p0+p1+x) ; write f32 + bf16 ----------------
__global__ __launch_bounds__(256) void ln_sum2(const float* __restrict__ parts,
                                               const float* __restrict__ res,
                                               const float* __restrict__ gam,
                                               const float* __restrict__ bet,
                                               float* __restrict__ of,
                                               u16* __restrict__ ob) {
  int w = threadIdx.x >> 6, lane = threadIdx.x & 63;
  int row = blockIdx.x * 4 + w;
  const float* p0 = parts + (size_t)row * DMODEL;
  const float* p1 = parts + (size_t)NTOK * DMODEL + (size_t)row * DMODEL;
  const float* pr = res + (size_t)row * DMODEL;
  float4 v[3];
  float s = 0.f, s2 = 0.f;
#pragma unroll
  for (int j = 0; j < 3; ++j) {
    int c = lane * 4 + j * 256;
    float4 a = *(const float4*)&p0[c];
    float4 b = *(const float4*)&p1[c];
    float4 r = *(const float4*)&pr[c];
    float4 t = {a.x + b.x + r.x, a.y + b.y + r.y, a.z + b.z + r.z, a.w + b.w + r.w};
    v[j] = t;
    s += t.x + t.y + t.z + t.w;
    s2 += t.x * t.x + t.y * t.y + t.z * t.z + t.w * t.w;
  }
#pragma unroll
  for (int off = 32; off; off >>= 1) {
    s += __shfl_xor(s, off);
    s2 += __shfl_xor(s2, off);
  }
  float mu = s * (1.f / DMODEL);
  float var = s2 * (1.f / DMODEL) - mu * mu;
  float rs = rsqrtf(var + 1e-5f);
#pragma unroll
  for (int j = 0; j < 3; ++j) {
    int c = lane * 4 + j * 256;
    float4 gm = *(const float4*)&gam[c];
    float4 bt = *(const float4*)&bet[c];
    float4 o = {(v[j].x - mu) * rs * gm.x + bt.x, (v[j].y - mu) * rs * gm.y + bt.y,
                (v[j].z - mu) * rs * gm.z + bt.z, (v[j].w - mu) * rs * gm.w + bt.w};
    *(float4*)&of[(size_t)row * DMODEL + c] = o;
    ushort4 ub = {f2b(o.x), f2b(o.y), f2b(o.z), f2b(o.w)};
    *(ushort4*)&ob[(size_t)row * DMODEL + c] = ub;
  }
}

// ---------------- LN2: layernorm(4 bf16 partials + b2 + res) -> f32 out ----------------
__global__ __launch_bounds__(256) void ln_sum4(const u16* __restrict__ pA,
                                               const u16* __restrict__ pB,
                                               const float* __restrict__ res,
                                               const float* __restrict__ badd,
                                               const float* __restrict__ gam,
                                               const float* __restrict__ bet,
                                               float* __restrict__ of) {
  int w = threadIdx.x >> 6, lane = threadIdx.x & 63;
  int row = blockIdx.x * 4 + w;
  size_t ro = (size_t)row * DMODEL;
  const size_t PS = (size_t)NTOK * DMODEL;
  float4 v[3];
  float s = 0.f, s2 = 0.f;
#pragma unroll
  for (int j = 0; j < 3; ++j) {
    int c = lane * 4 + j * 256;
    ushort4 u0 = *(const ushort4*)&pA[ro + c];
    ushort4 u1 = *(const ushort4*)&pA[PS + ro + c];
    ushort4 u2 = *(const ushort4*)&pB[ro + c];
    ushort4 u3 = *(const ushort4*)&pB[PS + ro + c];
    float4 r = *(const float4*)&res[ro + c];
    float4 bb = *(const float4*)&badd[c];
    float4 t = {b2f(u0.x) + b2f(u1.x) + b2f(u2.x) + b2f(u3.x) + r.x + bb.x,
                b2f(u0.y) + b2f(u1.y) + b2f(u2.y) + b2f(u3.y) + r.y + bb.y,
                b2f(u0.z) + b2f(u1.z) + b2f(u2.z) + b2f(u3.z) + r.z + bb.z,
                b2f(u0.w) + b2f(u1.w) + b2f(u2.w) + b2f(u3.w) + r.w + bb.w};
    v[j] = t;
    s += t.x + t.y + t.z + t.w;
    s2 += t.x * t.x + t.y * t.y + t.z * t.z + t.w * t.w;
  }
#pragma unroll
  for (int off = 32; off; off >>= 1) {
    s += __shfl_xor(s, off);
    s2 += __shfl_xor(s2, off);
  }
  float mu = s * (1.f / DMODEL);
  float var = s2 * (1.f / DMODEL) - mu * mu;
  float rs = rsqrtf(var + 1e-5f);
#pragma unroll
  for (int j = 0; j < 3; ++j) {
    int c = lane * 4 + j * 256;
    float4 gm = *(const float4*)&gam[c];
    float4 bt = *(const float4*)&bet[c];
    float4 o = {(v[j].x - mu) * rs * gm.x + bt.x, (v[j].y - mu) * rs * gm.y + bt.y,
                (v[j].z - mu) * rs * gm.z + bt.z, (v[j].w - mu) * rs * gm.w + bt.w};
    *(float4*)&of[ro + c] = o;
  }
}

// ---------------- launcher ----------------
extern "C" void kernel_launch(void* const* d_in, const int* in_sizes, int n_in,
                              void* d_out, int out_size, void* d_ws, size_t ws_size,
                              hipStream_t stream) {
  const float* x   = (const float*)d_in[0];
  const int*   msk = (const int*)d_in[1];
  const float* WQ  = (const float*)d_in[2];
  const float* WK  = (const float*)d_in[3];
  const float* WV  = (const float*)d_in[4];
  const float* Wfc = (const float*)d_in[5];
  const float* W1  = (const float*)d_in[6];
  const float* b1  = (const float*)d_in[7];
  const float* W2  = (const float*)d_in[8];
  const float* b2  = (const float*)d_in[9];
  const float* g1  = (const float*)d_in[10];
  const float* be1 = (const float*)d_in[11];
  const float* g2  = (const float*)d_in[12];
  const float* be2 = (const float*)d_in[13];
  float* out = (float*)d_out;

  char* ws = (char*)d_ws;
  u16*  XB    = (u16*)(ws + 0);          //  6291456
  u16*  WQKVT = (u16*)(ws + 6291456);    //  3538944
  u16*  WFCT  = (u16*)(ws + 9830400);    //  1179648
  u16*  W1T   = (u16*)(ws + 11010048);   //  4718592
  u16*  W2T   = (u16*)(ws + 15728640);   //  4718592
  u16*  QKVM  = (u16*)(ws + 20447232);   // 18874368
  u16*  VT    = (u16*)(ws + 39321600);   //  6291456
  u64*  MP    = (u64*)(ws + 45613056);   //   524288
  float* NAF  = (float*)(ws + 46137344); // 12582912
  u16*  NAB   = (u16*)(ws + 58720256);   //  6291456
  // overlays (liveness-checked):
  u16*   ATTO    = XB;
  float* PROJP   = (float*)QKVM;
  u16*   HMID    = QKVM;
  u16*   LINPA   = (u16*)(ws + 0);
  u16*   LINPB   = (u16*)(ws + 58720256);

  mega_prep<<<dim3(26368), dim3(256), 0, stream>>>(x, XB, WQ, WK, WV, Wfc, W1, W2,
                                                   WQKVT, WFCT, W1T, W2T, msk, MP);

  gemm_bt<0, 1><<<dim3(QKVN / 128, NTOK / 128, 1), dim3(256), 0, stream>>>(
      XB, WQKVT, QKVM, nullptr, nullptr, nullptr, NTOK, QKVN, DMODEL);
  build_vt<<<dim3(SEQ / 64, NHEAD, BSZ), dim3(256), 0, stream>>>(QKVM, VT);
  attn_kernel<<<dim3(BSZ * NHEAD * (SEQ / 64)), dim3(128), 0, stream>>>(QKVM, VT, MP, ATTO);

  gemm_bt<4, 2><<<dim3(DMODEL / 128, NTOK / 128, 2), dim3(256), 0, stream>>>(
      ATTO, WFCT, PROJP, nullptr, nullptr, nullptr, NTOK, DMODEL, DMODEL);
  ln_sum2<<<dim3(NTOK / 4), dim3(256), 0, stream>>>(PROJP, x, g1, be1, NAF, NAB);

  gemm_bt<2, 1><<<dim3(DFC / 128, NTOK / 128, 1), dim3(256), 0, stream>>>(
      NAB, W1T, HMID, b1, nullptr, nullptr, NTOK, DFC, DMODEL);
  gemm_bt<5, 4><<<dim3(DMODEL / 128, NTOK / 128, 4), dim3(256), 0, stream>>>(
      HMID, W2T, nullptr, nullptr, LINPA, LINPB, NTOK, DMODEL, DFC);
  ln_sum4<<<dim3(NTOK / 4), dim3(256), 0, stream>>>(LINPA, LINPB, NAF, b2, g2, be2, out);

  (void)in_sizes; (void)n_in; (void)out_size; (void)ws_size;
}